// Round 2
// baseline (1735.724 us; speedup 1.0000x reference)
//
#include <hip/hip_runtime.h>
#include <math.h>

// Problem constants (from reference): B=8, Tt=16, C=1, H=W=512, 4 in-channels, 10 T-planes.
#define Bd 8
#define Td 16
#define Hd 512
#define Wd 512
#define HWc (Hd * Wd)          // 262144
#define NPIX (Bd * HWc)        // 2,097,152

// ---------------------------------------------------------------------------
// Kernel 1: T = conv2d(x[:, -4:, 0], W_unet, SAME) + b_unet
// x layout: (B, 16, 1, 512, 512); input channels are time slices 12..15.
// T layout: (B, 10, 512, 512) in workspace.
// ---------------------------------------------------------------------------
__global__ void conv_T_kernel(const float* __restrict__ x,
                              const float* __restrict__ Wu,
                              const float* __restrict__ bu,
                              float* __restrict__ T) {
    __shared__ float sW[370];
    // blockDim.x = 256 < 370 -> must grid-stride the staging loop.
    for (int idx = threadIdx.x; idx < 370; idx += blockDim.x)
        sW[idx] = (idx < 360) ? Wu[idx] : bu[idx - 360];
    __syncthreads();

    int n = blockIdx.x * blockDim.x + threadIdx.x;
    if (n >= NPIX) return;
    int b   = n >> 18;          // / HWc
    int rem = n & (HWc - 1);
    int i   = rem >> 9;
    int j   = rem & (Wd - 1);

    const float* xb = x + ((size_t)b * Td + 12) * HWc;  // channel c -> slice 12+c
    float xv[4][3][3];
    #pragma unroll
    for (int c = 0; c < 4; ++c) {
        #pragma unroll
        for (int kh = 0; kh < 3; ++kh) {
            int ii = i + kh - 1;
            bool iv = (ii >= 0) && (ii < Hd);
            #pragma unroll
            for (int kw = 0; kw < 3; ++kw) {
                int jj = j + kw - 1;
                bool jv = (jj >= 0) && (jj < Wd);
                xv[c][kh][kw] = (iv && jv) ? xb[(size_t)c * HWc + ii * Wd + jj] : 0.0f;
            }
        }
    }

    float* Tb = T + (size_t)b * 10 * HWc + rem;
    #pragma unroll
    for (int o = 0; o < 10; ++o) {
        float acc = sW[360 + o];
        #pragma unroll
        for (int c = 0; c < 4; ++c)
            #pragma unroll
            for (int kh = 0; kh < 3; ++kh)
                #pragma unroll
                for (int kw = 0; kw < 3; ++kw)
                    acc += xv[c][kh][kw] * sW[((o * 4 + c) * 3 + kh) * 3 + kw];
        Tb[(size_t)o * HWc] = acc;
    }
}

// ---------------------------------------------------------------------------
// Kernel 2: one spatially-varying 3x3 stencil step (optionally + sigmoid).
// out[b,i,j] = T[b,9,i,j] + sum_k x[b, i+(k%3)-1, j+(k/3)-1] * T[b,k,i,j]
// (k = dj*3 + di per the reference's loop order; zero padding at borders).
// ---------------------------------------------------------------------------
template <bool SIG>
__global__ void step_kernel(const float* __restrict__ xin, size_t in_bstride,
                            const float* __restrict__ T,
                            float* __restrict__ xout, size_t out_bstride) {
    int n = blockIdx.x * blockDim.x + threadIdx.x;
    if (n >= NPIX) return;
    int b   = n >> 18;
    int rem = n & (HWc - 1);
    int i   = rem >> 9;
    int j   = rem & (Wd - 1);

    const float* xb = xin + (size_t)b * in_bstride;
    const float* Tb = T + (size_t)b * 10 * HWc + rem;

    float v[9];
    #pragma unroll
    for (int di = 0; di < 3; ++di) {          // row offset
        int ii = i + di - 1;
        bool iv = (ii >= 0) && (ii < Hd);
        #pragma unroll
        for (int dj = 0; dj < 3; ++dj) {      // col offset
            int jj = j + dj - 1;
            bool jv = (jj >= 0) && (jj < Wd);
            v[dj * 3 + di] = (iv && jv) ? xb[ii * Wd + jj] : 0.0f;
        }
    }

    float acc = Tb[(size_t)9 * HWc];
    #pragma unroll
    for (int k = 0; k < 9; ++k)
        acc += v[k] * Tb[(size_t)k * HWc];

    if (SIG) acc = 1.0f / (1.0f + __expf(-acc));
    xout[(size_t)b * out_bstride + rem] = acc;
}

// ---------------------------------------------------------------------------
// Workspace layout:
//   [0, 80MB)          : T  (B*10*H*W fp32)
//   [80MB, 88MB)       : ping buffer A (B*H*W fp32)
//   [88MB, 96MB)       : pong buffer B
// Requires ws_size >= 100,663,296 bytes.
// ---------------------------------------------------------------------------
extern "C" void kernel_launch(void* const* d_in, const int* in_sizes, int n_in,
                              void* d_out, int out_size, void* d_ws, size_t ws_size,
                              hipStream_t stream) {
    const float* x  = (const float*)d_in[0];
    const float* Wu = (const float*)d_in[1];
    const float* bu = (const float*)d_in[2];
    float* out = (float*)d_out;

    float* T    = (float*)d_ws;
    float* bufA = T + (size_t)Bd * 10 * HWc;
    float* bufB = bufA + (size_t)NPIX;

    const int threads = 256;
    const int blocks  = NPIX / threads;   // 8192

    conv_T_kernel<<<blocks, threads, 0, stream>>>(x, Wu, bu, T);

    // xt0 = step(x[:, 15, 0], T) -> out[:, 0]
    step_kernel<false><<<blocks, threads, 0, stream>>>(
        x + (size_t)15 * HWc, (size_t)Td * HWc, T, out, (size_t)Td * HWc);

    for (int t = 1; t < Td; ++t) {
        const float* prev = out + (size_t)(t - 1) * HWc;   // out slot t-1, stride 16*HW
        step_kernel<false><<<blocks, threads, 0, stream>>>(prev, (size_t)Td * HWc, T, bufA, (size_t)HWc);
        step_kernel<true ><<<blocks, threads, 0, stream>>>(bufA, (size_t)HWc,     T, bufB, (size_t)HWc);
        step_kernel<false><<<blocks, threads, 0, stream>>>(bufB, (size_t)HWc,     T, bufA, (size_t)HWc);
        step_kernel<true ><<<blocks, threads, 0, stream>>>(bufA, (size_t)HWc,     T, bufB, (size_t)HWc);
        step_kernel<false><<<blocks, threads, 0, stream>>>(bufB, (size_t)HWc,     T, bufA, (size_t)HWc);
        step_kernel<true ><<<blocks, threads, 0, stream>>>(bufA, (size_t)HWc,     T,
                                                           out + (size_t)t * HWc, (size_t)Td * HWc);
    }
}